// Round 3
// baseline (261.304 us; speedup 1.0000x reference)
//
#include <hip/hip_runtime.h>
#include <math.h>

#define D_GNN 256
#define ATTN  64
#define KNEI  16
#define NROWS 65536

constexpr float EPSV  = 1e-6f;
constexpr float SCALE = 0.125f;   // 64^-0.5

typedef __attribute__((ext_vector_type(8))) short bf16x8;
typedef __attribute__((ext_vector_type(4))) float f32x4;

__device__ __forceinline__ unsigned short f2bf(float f) {
    union { float f; unsigned u; } v; v.f = f;
    return (unsigned short)((v.u + 0x7FFFu + ((v.u >> 16) & 1u)) >> 16);
}
__device__ __forceinline__ float bf2f(unsigned short h) {
    union { unsigned u; float f; } v; v.u = ((unsigned)h) << 16;
    return v.f;
}

typedef __attribute__((address_space(3))) short lds_short;
typedef __attribute__((address_space(1))) const short gm_short;
__device__ __forceinline__ void gload16(const unsigned short* g, short* l) {
    __builtin_amdgcn_global_load_lds((gm_short*)g, (lds_short*)l, 16, 0, 0);
}

// ---------------------------------------------------------------------------
// prep: center fp32 -> bf16 (4 elems/thread)
// ---------------------------------------------------------------------------
__global__ __launch_bounds__(256) void conv_C_bf16(const float* __restrict__ in,
                                                   unsigned short* __restrict__ out) {
    size_t i = (size_t)blockIdx.x * 256 + threadIdx.x;
    float4 v = ((const float4*)in)[i];
    short4 o;
    o.x = (short)f2bf(v.x); o.y = (short)f2bf(v.y);
    o.z = (short)f2bf(v.z); o.w = (short)f2bf(v.w);
    ((short4*)out)[i] = o;
}

// ---------------------------------------------------------------------------
// Mt[j][i] = (Wq @ Wk^T)[i][j] in bf16  (stored transposed = B cols k-contig)
// ---------------------------------------------------------------------------
__global__ __launch_bounds__(256) void build_Mt(const float* __restrict__ Wq,
                                                const float* __restrict__ Wk,
                                                unsigned short* __restrict__ Mt) {
    __shared__ float wq[ATTN];
    int i = blockIdx.x;
    int j = threadIdx.x;
    if (j < ATTN) wq[j] = Wq[i * ATTN + j];
    __syncthreads();
    float s = 0.f;
#pragma unroll
    for (int a = 0; a < ATTN; ++a) s = fmaf(wq[a], Wk[j * ATTN + a], s);
    Mt[j * D_GNN + i] = f2bf(s);
}

// ---------------------------------------------------------------------------
// WgT[j][k] = Wg[k][j] in bf16   (j<256, k<512)
// ---------------------------------------------------------------------------
__global__ __launch_bounds__(256) void conv_WgT(const float* __restrict__ Wg,
                                                unsigned short* __restrict__ WgT) {
    int k = blockIdx.x;       // 0..511
    int j = threadIdx.x;      // 0..255
    WgT[j * 512 + k] = f2bf(Wg[k * D_GNN + j]);
}

// ---------------------------------------------------------------------------
// P = Cbf @ Mt^T  -> Pbf [65536,256] bf16.  128x128 tile, BK=64, 4 waves.
// ---------------------------------------------------------------------------
__global__ __launch_bounds__(256) void gemm_P_mfma(const unsigned short* __restrict__ Abf,
                                                   const unsigned short* __restrict__ Bt,
                                                   unsigned short* __restrict__ Pbf) {
    __shared__ short As[128 * 64];
    __shared__ short Bs[128 * 64];
    const int tid  = threadIdx.x;
    const int lane = tid & 63;
    const int wid  = tid >> 6;
    const int wr   = wid >> 1, wc = wid & 1;
    const int l15  = lane & 15, lg = lane >> 4;
    const int brow = blockIdx.x * 128;
    const int bcol = blockIdx.y * 128;

    f32x4 acc[4][4] = {};

    for (int k0 = 0; k0 < D_GNN; k0 += 64) {
#pragma unroll
        for (int is = 0; is < 4; ++is) {
            int off  = is * 4096 + tid * 16;     // byte offset in 16KB tile
            int row  = off >> 7;                 // 128 B per row
            int cs   = (off & 127) >> 1;         // short within row
            int lofs = is * 2048 + wid * 512;    // shorts, wave-uniform
            gload16(Abf + (size_t)(brow + row) * D_GNN + k0 + cs, As + lofs);
            gload16(Bt  + (size_t)(bcol + row) * D_GNN + k0 + cs, Bs + lofs);
        }
        __syncthreads();
#pragma unroll
        for (int kk = 0; kk < 64; kk += 32) {
            bf16x8 af[4], bq[4];
#pragma unroll
            for (int m = 0; m < 4; ++m)
                af[m] = *(const bf16x8*)&As[(wr * 64 + m * 16 + l15) * 64 + kk + lg * 8];
#pragma unroll
            for (int n = 0; n < 4; ++n)
                bq[n] = *(const bf16x8*)&Bs[(wc * 64 + n * 16 + l15) * 64 + kk + lg * 8];
#pragma unroll
            for (int m = 0; m < 4; ++m)
#pragma unroll
                for (int n = 0; n < 4; ++n)
                    acc[m][n] = __builtin_amdgcn_mfma_f32_16x16x32_bf16(af[m], bq[n], acc[m][n], 0, 0, 0);
        }
        __syncthreads();
    }
#pragma unroll
    for (int m = 0; m < 4; ++m) {
        int row0 = brow + wr * 64 + m * 16 + lg * 4;
#pragma unroll
        for (int n = 0; n < 4; ++n) {
            int col = bcol + wc * 64 + n * 16 + l15;
#pragma unroll
            for (int r = 0; r < 4; ++r)
                Pbf[(size_t)(row0 + r) * D_GNN + col] = f2bf(acc[m][n][r]);
        }
    }
}

// ---------------------------------------------------------------------------
// gather + scores + softmax + weighted sum -> Wbf [65536,256] bf16
// 1 wave per row, 4 rows per block.
// Multi-value reduce-scatter: lane l ends with score for
//   k(l) = 8*b4 + 4*b5 + 2*b0 + b1   (b_i = bit i of lane)
// then distributed softmax over lane-bits {0,1,4,5}, readlane broadcasts.
// ---------------------------------------------------------------------------
__global__ __launch_bounds__(256, 4) void gather_attn(const unsigned short* __restrict__ Pbf,
                                                      unsigned short* __restrict__ Wbf,
                                                      const float* __restrict__ allE,
                                                      const int* __restrict__ nidx,
                                                      const float* __restrict__ nw) {
    int lane = threadIdx.x & 63;
    int wid  = threadIdx.x >> 6;
    int b    = blockIdx.x * 4 + wid;

    short4 pq = ((const short4*)(Pbf + (size_t)b * D_GNN))[lane];
    float4 p4 = { bf2f((unsigned short)pq.x), bf2f((unsigned short)pq.y),
                  bf2f((unsigned short)pq.z), bf2f((unsigned short)pq.w) };

    // wave-uniform neighbor indices (scalar loads)
    int idxs[KNEI];
#pragma unroll
    for (int k = 0; k < KNEI; ++k) idxs[k] = nidx[b * KNEI + k];

    // gather all 16 rows into registers, compute per-lane dot partials
    float4 nv[KNEI];
    float  sc[KNEI];
#pragma unroll
    for (int k = 0; k < KNEI; ++k)
        nv[k] = ((const float4*)(allE + (size_t)idxs[k] * D_GNN))[lane];
#pragma unroll
    for (int k = 0; k < KNEI; ++k)
        sc[k] = p4.x * nv[k].x + p4.y * nv[k].y + p4.z * nv[k].z + p4.w * nv[k].w;

    // reduce-scatter butterfly: 17 shuffles total
    float t8[8];
#pragma unroll
    for (int j = 0; j < 8; ++j) {
        float send = (lane & 16) ? sc[j] : sc[j + 8];
        float keep = (lane & 16) ? sc[j + 8] : sc[j];
        t8[j] = keep + __shfl_xor(send, 16);
    }
    float t4[4];
#pragma unroll
    for (int j = 0; j < 4; ++j) {
        float send = (lane & 32) ? t8[j] : t8[j + 4];
        float keep = (lane & 32) ? t8[j + 4] : t8[j];
        t4[j] = keep + __shfl_xor(send, 32);
    }
    float t2[2];
#pragma unroll
    for (int j = 0; j < 2; ++j) {
        float send = (lane & 1) ? t4[j] : t4[j + 2];
        float keep = (lane & 1) ? t4[j + 2] : t4[j];
        t2[j] = keep + __shfl_xor(send, 1);
    }
    float s1;
    {
        float send = (lane & 2) ? t2[0] : t2[1];
        float keep = (lane & 2) ? t2[1] : t2[0];
        s1 = keep + __shfl_xor(send, 2);
    }
    s1 += __shfl_xor(s1, 4);
    s1 += __shfl_xor(s1, 8);
    // lane l now holds full score for k(l)
    int kidx = ((lane >> 4) & 1) * 8 + ((lane >> 5) & 1) * 4 + (lane & 1) * 2 + ((lane >> 1) & 1);

    float w = nw[b * KNEI + kidx];
    float s = (w < EPSV) ? -INFINITY : fmaf(s1, SCALE, logf(w));

    // distributed softmax over lane-bits {0,1,4,5} (= the 16 k values)
    float mx = s;
    mx = fmaxf(mx, __shfl_xor(mx, 1));
    mx = fmaxf(mx, __shfl_xor(mx, 2));
    mx = fmaxf(mx, __shfl_xor(mx, 16));
    mx = fmaxf(mx, __shfl_xor(mx, 32));
    float e = (mx > -INFINITY) ? expf(s - mx) : 0.f;   // guards all-padded row
    float den = e;
    den += __shfl_xor(den, 1);
    den += __shfl_xor(den, 2);
    den += __shfl_xor(den, 16);
    den += __shfl_xor(den, 32);
    float a = (mx > -INFINITY) ? e / den : 0.f;

    // broadcast the 16 attention weights (constant src lane -> v_readlane)
    float4 acc = {0.f, 0.f, 0.f, 0.f};
#pragma unroll
    for (int k = 0; k < KNEI; ++k) {
        int src = (((k >> 3) & 1) << 4) | (((k >> 2) & 1) << 5) | ((k >> 1) & 1) | ((k & 1) << 1);
        float ak = __shfl(a, src);
        acc.x = fmaf(ak, nv[k].x, acc.x);
        acc.y = fmaf(ak, nv[k].y, acc.y);
        acc.z = fmaf(ak, nv[k].z, acc.z);
        acc.w = fmaf(ak, nv[k].w, acc.w);
    }

    short4 o;
    o.x = (short)f2bf(acc.x); o.y = (short)f2bf(acc.y);
    o.z = (short)f2bf(acc.z); o.w = (short)f2bf(acc.w);
    ((short4*)(Wbf + (size_t)b * D_GNN))[lane] = o;
}

// ---------------------------------------------------------------------------
// gate = sigmoid([C|W] @ Wg + bg); out = g*C + (1-g)*W.  K=512 (C half, W half)
// ---------------------------------------------------------------------------
__global__ __launch_bounds__(256) void gate_gemm_mfma(const unsigned short* __restrict__ Cbf,
                                                      const unsigned short* __restrict__ Wbf,
                                                      const unsigned short* __restrict__ WgT,
                                                      const float* __restrict__ C32,
                                                      const float* __restrict__ bg,
                                                      float* __restrict__ Out) {
    __shared__ short As[128 * 64];
    __shared__ short Bs[128 * 64];
    const int tid  = threadIdx.x;
    const int lane = tid & 63;
    const int wid  = tid >> 6;
    const int wr   = wid >> 1, wc = wid & 1;
    const int l15  = lane & 15, lg = lane >> 4;
    const int brow = blockIdx.x * 128;
    const int bcol = blockIdx.y * 128;

    f32x4 acc[4][4] = {};

    for (int k0 = 0; k0 < 2 * D_GNN; k0 += 64) {
        const unsigned short* Asrc = (k0 < D_GNN) ? Cbf : Wbf;
        int koff = k0 & (D_GNN - 1);
#pragma unroll
        for (int is = 0; is < 4; ++is) {
            int off  = is * 4096 + tid * 16;
            int row  = off >> 7;
            int cs   = (off & 127) >> 1;
            int lofs = is * 2048 + wid * 512;
            gload16(Asrc + (size_t)(brow + row) * D_GNN + koff + cs, As + lofs);
            gload16(WgT  + (size_t)(bcol + row) * 512 + k0 + cs,   Bs + lofs);
        }
        __syncthreads();
#pragma unroll
        for (int kk = 0; kk < 64; kk += 32) {
            bf16x8 af[4], bq[4];
#pragma unroll
            for (int m = 0; m < 4; ++m)
                af[m] = *(const bf16x8*)&As[(wr * 64 + m * 16 + l15) * 64 + kk + lg * 8];
#pragma unroll
            for (int n = 0; n < 4; ++n)
                bq[n] = *(const bf16x8*)&Bs[(wc * 64 + n * 16 + l15) * 64 + kk + lg * 8];
#pragma unroll
            for (int m = 0; m < 4; ++m)
#pragma unroll
                for (int n = 0; n < 4; ++n)
                    acc[m][n] = __builtin_amdgcn_mfma_f32_16x16x32_bf16(af[m], bq[n], acc[m][n], 0, 0, 0);
        }
        __syncthreads();
    }
#pragma unroll
    for (int m = 0; m < 4; ++m) {
        int row0 = brow + wr * 64 + m * 16 + lg * 4;
#pragma unroll
        for (int n = 0; n < 4; ++n) {
            int col = bcol + wc * 64 + n * 16 + l15;
            float bgc = bg[col];
#pragma unroll
            for (int r = 0; r < 4; ++r) {
                size_t rr = (size_t)(row0 + r);
                float g  = 1.f / (1.f + expf(-(acc[m][n][r] + bgc)));
                float cv = C32[rr * D_GNN + col];
                float wv = bf2f(Wbf[rr * D_GNN + col]);
                Out[rr * D_GNN + col] = fmaf(g, cv - wv, wv);
            }
        }
    }
}

// ---------------------------------------------------------------------------
extern "C" void kernel_launch(void* const* d_in, const int* in_sizes, int n_in,
                              void* d_out, int out_size, void* d_ws, size_t ws_size,
                              hipStream_t stream) {
    const float* center = (const float*)d_in[0];
    const float* allE   = (const float*)d_in[1];
    const int*   nidx   = (const int*)d_in[2];
    const float* nw     = (const float*)d_in[3];
    const float* Wq     = (const float*)d_in[4];
    const float* Wk     = (const float*)d_in[5];
    const float* Wg     = (const float*)d_in[6];
    const float* bg     = (const float*)d_in[7];
    float* out = (float*)d_out;

    // ws layout (bf16): Cbf | Wbf | Pbf | Mt | WgT   (~96.3 MB total)
    unsigned short* Cbf = (unsigned short*)d_ws;
    unsigned short* Wbf = Cbf + (size_t)NROWS * D_GNN;
    unsigned short* Pbf = Wbf + (size_t)NROWS * D_GNN;
    unsigned short* Mt  = Pbf + (size_t)NROWS * D_GNN;
    unsigned short* WgT = Mt + D_GNN * D_GNN;

    conv_C_bf16   <<<dim3(NROWS * D_GNN / 1024), dim3(256), 0, stream>>>(center, Cbf);
    build_Mt      <<<dim3(D_GNN),                dim3(256), 0, stream>>>(Wq, Wk, Mt);
    conv_WgT      <<<dim3(2 * D_GNN),            dim3(256), 0, stream>>>(Wg, WgT);
    gemm_P_mfma   <<<dim3(NROWS / 128, 2),       dim3(256), 0, stream>>>(Cbf, Mt, Pbf);
    gather_attn   <<<dim3(NROWS / 4),            dim3(256), 0, stream>>>(Pbf, Wbf, allE, nidx, nw);
    gate_gemm_mfma<<<dim3(NROWS / 128, 2),       dim3(256), 0, stream>>>(Cbf, Wbf, WgT, center, bg, out);
}